// Round 1
// baseline (637.082 us; speedup 1.0000x reference)
//
#include <hip/hip_runtime.h>

// ---------------------------------------------------------------------------
// CrossAttention on MI355X (gfx950), bf16 MFMA, fully fused.
//
// Key structural facts exploited:
//  * a_o = softmax over j-axis of size 1  ==> a_o == 1, so
//    out_o[b,l] = x_e @ (Wv_ego @ W_out_other) + b_out_other  (same for all l).
//    q_o and k_e are never needed.
//  * Everything else is per-(b,k,pixel) independent: q_e = x_e@Wq,
//    {k_o,v_o} = x_o@Wkv, 1x8 attention over agents, out_e = att@W_out_ego.
//
// One block per (b, k, n-half=32 pixels); 256 threads (4 waves).
// X tiles staged to LDS transposed [n][c] (bf16, stride 264 => 16B-aligned
// b128 fragment reads). Weights pre-transposed to bf16 WT[o][c] in ws.
// MFMA 16x16x32 bf16: A = WT rows (A[m=lane&15][k=quad*8+j]),
// B = X rows ([n=lane&15][k consec]), D[o][n]: col=lane&15, row=quad*4+reg.
// ---------------------------------------------------------------------------

typedef unsigned short u16;
typedef u16  u16x8 __attribute__((ext_vector_type(8)));
typedef u16  u16x4 __attribute__((ext_vector_type(4)));
typedef __bf16 bf16x8 __attribute__((ext_vector_type(8)));
typedef float f32x4 __attribute__((ext_vector_type(4)));

#define XS  264   // LDS stride (elements) for 256-wide X tiles (multiple of 8)
#define KVS 520   // LDS stride for 512-wide KV tile (multiple of 8)

__device__ __forceinline__ u16 f2bf(float f) {
  union { float f; unsigned u; } t; t.f = f;
  unsigned r = t.u + 0x7FFF + ((t.u >> 16) & 1);   // RTN-even
  return (u16)(r >> 16);
}
__device__ __forceinline__ float bf2f(u16 x) {
  union { unsigned u; float f; } t; t.u = ((unsigned)x) << 16;
  return t.f;
}

// GEMM: D[o][n] = sum_c WT[o][c] * X[n][c], M = MT*4*16 rows, N = 32, K = 256.
// Wave w owns mtiles [w*MT, (w+1)*MT). acc[mt][nt] is the 16x16 tile.
template <int MT>
__device__ __forceinline__ void gemm_run(const u16* __restrict__ WT,
                                         const u16* __restrict__ X,
                                         int wave, int col, int quad,
                                         f32x4 (&acc)[MT][2]) {
#pragma unroll
  for (int mt = 0; mt < MT; ++mt)
#pragma unroll
    for (int nt = 0; nt < 2; ++nt)
      acc[mt][nt] = (f32x4)(0.0f);

  for (int ks = 0; ks < 8; ++ks) {
    bf16x8 bfr[2];
#pragma unroll
    for (int nt = 0; nt < 2; ++nt)
      bfr[nt] = __builtin_bit_cast(
          bf16x8, *(const u16x8*)&X[(nt * 16 + col) * XS + ks * 32 + quad * 8]);
#pragma unroll
    for (int mt = 0; mt < MT; ++mt) {
      const int m = (wave * MT + mt) * 16 + col;
      bf16x8 afr = __builtin_bit_cast(
          bf16x8, *(const u16x8*)&WT[m * 256 + ks * 32 + quad * 8]);
#pragma unroll
      for (int nt = 0; nt < 2; ++nt)
        acc[mt][nt] = __builtin_amdgcn_mfma_f32_16x16x32_bf16(
            afr, bfr[nt], acc[mt][nt], 0, 0, 0);
    }
  }
}

// ---------------------------------------------------------------------------
// Setup kernel 1: WfusedT[o][c] = (Wv_ego @ W_out_other)^T, bf16, in ws.
// Wv_ego[c][j] = W_qkv_ego[c*768 + 512 + j].
// ---------------------------------------------------------------------------
__global__ void ca_setup_fuse(const float* __restrict__ Wqkv_e,
                              const float* __restrict__ Woo,
                              u16* __restrict__ WCQ) {
  const int c = blockIdx.x;    // 0..255
  const int o = threadIdx.x;   // 0..255
  __shared__ float wv[256];
  wv[o] = Wqkv_e[c * 768 + 512 + o];
  __syncthreads();
  float s = 0.f;
#pragma unroll 4
  for (int j = 0; j < 256; ++j) s += wv[j] * Woo[j * 256 + o];
  WCQ[o * 256 + c] = f2bf(s);  // rows 0..255 of WCQ = WfusedT
}

// ---------------------------------------------------------------------------
// Setup kernel 2: plain transposes to bf16 WT[o][c] layouts.
//  sec 0: WCQ rows 256..511 = WqT   (W_qkv_ego cols 0..255)
//  sec 1: WKV rows 0..255   = WkoT  (W_qkv_other cols 256..511)
//  sec 2: WKV rows 256..511 = WvoT  (W_qkv_other cols 512..767)
//  sec 3: WOE rows 0..255   = WoeT  (W_out_ego)
// ---------------------------------------------------------------------------
__global__ void ca_setup_trans(const float* __restrict__ Wqkv_e,
                               const float* __restrict__ Wqkv_o,
                               const float* __restrict__ Woe,
                               u16* __restrict__ WCQ, u16* __restrict__ WKV,
                               u16* __restrict__ WOET) {
  const int id = blockIdx.x;    // 0..1023
  const int c = threadIdx.x;    // 0..255
  const int o = id & 255;
  const int sec = id >> 8;
  if (sec == 0)      WCQ[(256 + o) * 256 + c] = f2bf(Wqkv_e[c * 768 + o]);
  else if (sec == 1) WKV[o * 256 + c]         = f2bf(Wqkv_o[c * 768 + 256 + o]);
  else if (sec == 2) WKV[(256 + o) * 256 + c] = f2bf(Wqkv_o[c * 768 + 512 + o]);
  else               WOET[o * 256 + c]        = f2bf(Woe[c * 256 + o]);
}

// ---------------------------------------------------------------------------
// Main fused kernel. Grid = 8*32*2 = 512 blocks, 256 threads.
// ---------------------------------------------------------------------------
__global__ __launch_bounds__(256, 2) void ca_main(
    const float* __restrict__ ego, const float* __restrict__ other,
    const float* __restrict__ b_oe, const float* __restrict__ b_oo,
    const u16* __restrict__ WCQ, const u16* __restrict__ WKV,
    const u16* __restrict__ WOE, float* __restrict__ out) {
  const int gid = blockIdx.x;
  const int b  = gid >> 6;
  const int kk = (gid >> 1) & 31;
  const int nh = gid & 1;
  const int t = threadIdx.x;
  const int lane = t & 63, wave = t >> 6;
  const int col = lane & 15, quad = lane >> 4;

  // LDS arena (50176 B):
  //  xbuf: Xe -> Xo(l) -> Att   [32][XS]
  //  kbuf: Q ([32][XS]) -> KV ([32][KVS])
  __shared__ u16 smem[32 * XS + 32 * KVS];
  u16* xbuf = smem;
  u16* kbuf = smem + 32 * XS;

  // stage 32 pixels x 256 channels from [C][64-pix] global layout into
  // LDS [n][c] bf16 (transpose): 8 coalesced loads + one b128 write per iter.
  auto stage = [&](const float* __restrict__ src) {
    const int n = t & 31, cg = t >> 5;
#pragma unroll
    for (int it = 0; it < 4; ++it) {
      const int c0 = it * 64 + cg * 8;
      u16x8 p;
#pragma unroll
      for (int j = 0; j < 8; ++j) p[j] = f2bf(src[(c0 + j) * 64 + n]);
      *(u16x8*)&xbuf[n * XS + c0] = p;
    }
  };

  // ---- Phase A: Xe -> {out_common (broadcast to out_o), Q_e} --------------
  stage(ego + ((b * 32 + kk) * 256) * 64 + nh * 32);
  __syncthreads();
  {
    f32x4 acc[8][2];
    gemm_run<8>(WCQ, xbuf, wave, col, quad, acc);
    if (wave < 2) {
      float* outO = out + 4194304;  // out_o section
#pragma unroll
      for (int mt = 0; mt < 8; ++mt) {
        const int ob = (wave * 8 + mt) * 16 + quad * 4;
#pragma unroll
        for (int nt = 0; nt < 2; ++nt) {
          const int n = nh * 32 + nt * 16 + col;
#pragma unroll
          for (int r = 0; r < 4; ++r) {
            const float v = acc[mt][nt][r] + b_oo[ob + r];
            const int base = ((b * 8) * 32 + kk) * 16384 + (ob + r) * 64 + n;
#pragma unroll
            for (int l = 0; l < 8; ++l)
              outO[base + l * 524288] = v;   // l stride = 32*16384
          }
        }
      }
    } else {
      // Q rows 0..255 -> kbuf[n][o] (transposed write, 4 consecutive o)
#pragma unroll
      for (int mt = 0; mt < 8; ++mt) {
        const int ob = ((wave - 2) * 8 + mt) * 16 + quad * 4;
#pragma unroll
        for (int nt = 0; nt < 2; ++nt) {
          const int n = nt * 16 + col;
          u16x4 p;
#pragma unroll
          for (int r = 0; r < 4; ++r) p[r] = f2bf(acc[mt][nt][r]);
          *(u16x4*)&kbuf[n * XS + ob] = p;
        }
      }
    }
  }
  __syncthreads();

  // ---- load q into registers (thread (n, h)) ------------------------------
  const int an = t & 31, ah = t >> 5;
  float qf[32];
#pragma unroll
  for (int jj = 0; jj < 4; ++jj) {
    u16x8 u = *(const u16x8*)&kbuf[an * XS + ah * 32 + jj * 8];
#pragma unroll
    for (int e = 0; e < 8; ++e) qf[jj * 8 + e] = bf2f(u[e]);
  }
  __syncthreads();

  // ---- Phase B: loop over 8 agents, online softmax ------------------------
  float m_run = -3.0e38f, s_run = 0.f;
  float oacc[32];
#pragma unroll
  for (int c = 0; c < 32; ++c) oacc[c] = 0.f;

  for (int l = 0; l < 8; ++l) {
    stage(other + (((b * 8 + l) * 32 + kk) * 256) * 64 + nh * 32);
    __syncthreads();
    {
      f32x4 acc[8][2];
      gemm_run<8>(WKV, xbuf, wave, col, quad, acc);
#pragma unroll
      for (int mt = 0; mt < 8; ++mt) {
        const int ob = (wave * 8 + mt) * 16 + quad * 4;
#pragma unroll
        for (int nt = 0; nt < 2; ++nt) {
          const int n = nt * 16 + col;
          u16x4 p;
#pragma unroll
          for (int r = 0; r < 4; ++r) p[r] = f2bf(acc[mt][nt][r]);
          *(u16x4*)&kbuf[n * KVS + ob] = p;   // K at o<256, V at o>=256
        }
      }
    }
    __syncthreads();

    // attention update for this agent
    float sc = 0.f;
#pragma unroll
    for (int jj = 0; jj < 4; ++jj) {
      u16x8 u = *(const u16x8*)&kbuf[an * KVS + ah * 32 + jj * 8];
#pragma unroll
      for (int e = 0; e < 8; ++e) sc += qf[jj * 8 + e] * bf2f(u[e]);
    }
    sc *= 0.17677669529663687f;  // 1/sqrt(32)
    const float mnew = fmaxf(m_run, sc);
    const float p = __expf(sc - mnew);
    const float al = __expf(m_run - mnew);
    s_run = s_run * al + p;
#pragma unroll
    for (int jj = 0; jj < 4; ++jj) {
      u16x8 u = *(const u16x8*)&kbuf[an * KVS + 256 + ah * 32 + jj * 8];
#pragma unroll
      for (int e = 0; e < 8; ++e)
        oacc[jj * 8 + e] = oacc[jj * 8 + e] * al + p * bf2f(u[e]);
    }
    m_run = mnew;
    __syncthreads();
  }

  // ---- write normalized attention output to LDS [n][h*32+c] ---------------
  {
    const float inv = 1.f / s_run;
#pragma unroll
    for (int jj = 0; jj < 4; ++jj) {
      u16x8 p;
#pragma unroll
      for (int e = 0; e < 8; ++e) p[e] = f2bf(oacc[jj * 8 + e] * inv);
      *(u16x8*)&xbuf[an * XS + ah * 32 + jj * 8] = p;
    }
  }
  __syncthreads();

  // ---- Phase C: out_e = Att @ W_out_ego + b -------------------------------
  {
    f32x4 acc[4][2];
    gemm_run<4>(WOE, xbuf, wave, col, quad, acc);
#pragma unroll
    for (int mt = 0; mt < 4; ++mt) {
      const int ob = (wave * 4 + mt) * 16 + quad * 4;
#pragma unroll
      for (int nt = 0; nt < 2; ++nt) {
        const int n = nh * 32 + nt * 16 + col;
#pragma unroll
        for (int r = 0; r < 4; ++r)
          out[((b * 32 + kk) * 256 + ob + r) * 64 + n] =
              acc[mt][nt][r] + b_oe[ob + r];
      }
    }
  }
}

// ---------------------------------------------------------------------------
extern "C" void kernel_launch(void* const* d_in, const int* in_sizes, int n_in,
                              void* d_out, int out_size, void* d_ws,
                              size_t ws_size, hipStream_t stream) {
  const float* ego    = (const float*)d_in[0];
  const float* other  = (const float*)d_in[1];
  const float* Wqkv_e = (const float*)d_in[2];
  const float* Wqkv_o = (const float*)d_in[3];
  const float* Woe    = (const float*)d_in[4];
  const float* boe    = (const float*)d_in[5];
  const float* Woo    = (const float*)d_in[6];
  const float* boo    = (const float*)d_in[7];
  float* out = (float*)d_out;

  u16* WCQ  = (u16*)d_ws;            // [512][256]: WfusedT ; WqT
  u16* WKV  = WCQ + 512 * 256;       // [512][256]: WkoT ; WvoT
  u16* WOET = WKV + 512 * 256;       // [256][256]: WoeT

  ca_setup_fuse<<<256, 256, 0, stream>>>(Wqkv_e, Woo, WCQ);
  ca_setup_trans<<<1024, 256, 0, stream>>>(Wqkv_e, Wqkv_o, Woe, WCQ, WKV, WOET);
  ca_main<<<512, 256, 0, stream>>>(ego, other, boe, boo, WCQ, WKV, WOET, out);
}

// Round 2
// 493.553 us; speedup vs baseline: 1.2908x; 1.2908x over previous
//
#include <hip/hip_runtime.h>

// ---------------------------------------------------------------------------
// CrossAttention on MI355X (gfx950) — round 2: de-serialized 3-kernel pipeline.
//
// Structural facts:
//  * a_o = softmax over a size-1 axis == 1  =>  out_o[b,l] = x_e @ (Wv_ego @
//    W_out_other) + b_oo, identical over l (broadcast 8x). q_o,k_e unused.
//  * KV = x_o @ Wkv_other is a big parallel GEMM (34 GF) — move it out of the
//    per-(b,k) serialized agent loop into 4096 independent blocks.
//  * Attention (softmax over 8 agents) is tiny per-pixel register work; do it
//    with zero LDS / zero barriers, prefetching agent l+1 while doing l.
//
// ws layout: [WCQ 512x256 bf16][WKV 512x256][WOE 256x256][Q nk*64x256][KV nk*8*64x512]
// Launcher auto-chunks the 256-wide (b,k) axis so ws always fits.
// ---------------------------------------------------------------------------

typedef unsigned short u16;
typedef u16  u16x8 __attribute__((ext_vector_type(8)));
typedef u16  u16x4 __attribute__((ext_vector_type(4)));
typedef __bf16 bf16x8 __attribute__((ext_vector_type(8)));
typedef float f32x4 __attribute__((ext_vector_type(4)));

#define XS  264   // LDS stride for 256-wide tiles (x2B = 528B rows, 16B-aligned)
#define KVS 520   // LDS stride for 512-wide KV tile

__device__ __forceinline__ u16 f2bf(float f) {
  union { float f; unsigned u; } t; t.f = f;
  unsigned r = t.u + 0x7FFF + ((t.u >> 16) & 1);
  return (u16)(r >> 16);
}
__device__ __forceinline__ float bf2f(u16 x) {
  union { unsigned u; float f; } t; t.u = ((unsigned)x) << 16;
  return t.f;
}

// D[o][n] = sum_c WT[o][c]*X[n][c]; M = MT*4*16, N = 32, K = 256.
template <int MT>
__device__ __forceinline__ void gemm_run(const u16* __restrict__ WT,
                                         const u16* __restrict__ X,
                                         int wave, int col, int quad,
                                         f32x4 (&acc)[MT][2]) {
#pragma unroll
  for (int mt = 0; mt < MT; ++mt)
#pragma unroll
    for (int nt = 0; nt < 2; ++nt)
      acc[mt][nt] = (f32x4)(0.0f);
  for (int ks = 0; ks < 8; ++ks) {
    bf16x8 bfr[2];
#pragma unroll
    for (int nt = 0; nt < 2; ++nt)
      bfr[nt] = __builtin_bit_cast(
          bf16x8, *(const u16x8*)&X[(nt * 16 + col) * XS + ks * 32 + quad * 8]);
#pragma unroll
    for (int mt = 0; mt < MT; ++mt) {
      const int m = (wave * MT + mt) * 16 + col;
      bf16x8 afr = __builtin_bit_cast(
          bf16x8, *(const u16x8*)&WT[m * 256 + ks * 32 + quad * 8]);
#pragma unroll
      for (int nt = 0; nt < 2; ++nt)
        acc[mt][nt] = __builtin_amdgcn_mfma_f32_16x16x32_bf16(
            afr, bfr[nt], acc[mt][nt], 0, 0, 0);
    }
  }
}

// ---------------------------------------------------------------------------
// Setup: WCQ row layout interleaves fused/q rows per 64-row group so each
// wave (128 rows) gets 64 fused rows + 64 q rows (balanced epilogue work).
//   group g = row>>6: even -> fused row (g>>1)*64+off ; odd -> q row.
// ---------------------------------------------------------------------------
__global__ void ca_setup_fuse(const float* __restrict__ Wqkv_e,
                              const float* __restrict__ Woo,
                              u16* __restrict__ WCQ) {
  const int c = blockIdx.x, o = threadIdx.x;
  __shared__ float wv[256];
  wv[o] = Wqkv_e[c * 768 + 512 + o];
  __syncthreads();
  float s = 0.f;
#pragma unroll 8
  for (int j = 0; j < 256; ++j) s += wv[j] * Woo[j * 256 + o];
  const int row = (o >> 6) * 128 + (o & 63);          // fused row o
  WCQ[row * 256 + c] = f2bf(s);
}

__global__ void ca_setup_trans(const float* __restrict__ Wqkv_e,
                               const float* __restrict__ Wqkv_o,
                               const float* __restrict__ Woe,
                               u16* __restrict__ WCQ, u16* __restrict__ WKV,
                               u16* __restrict__ WOET) {
  const int id = blockIdx.x;    // 0..1023
  const int c = threadIdx.x;    // 0..255
  const int o = id & 255;
  const int sec = id >> 8;
  if (sec == 0) {               // q row o -> interleaved slot
    const int row = (o >> 6) * 128 + 64 + (o & 63);
    WCQ[row * 256 + c] = f2bf(Wqkv_e[c * 768 + o]);
  } else if (sec == 1) WKV[o * 256 + c]         = f2bf(Wqkv_o[c * 768 + 256 + o]);
  else if (sec == 2)   WKV[(256 + o) * 256 + c] = f2bf(Wqkv_o[c * 768 + 512 + o]);
  else                 WOET[o * 256 + c]        = f2bf(Woe[c * 256 + o]);
}

// stage 32 pixels x 256 ch from [C][64] f32 into LDS [n][c] bf16
__device__ __forceinline__ void stage_x(const float* __restrict__ src,
                                        u16* __restrict__ xbuf, int t) {
  const int n = t & 31, cg = t >> 5;
#pragma unroll
  for (int it = 0; it < 4; ++it) {
    const int c0 = it * 64 + cg * 8;
    u16x8 p;
#pragma unroll
    for (int j = 0; j < 8; ++j) p[j] = f2bf(src[(c0 + j) * 64 + n]);
    *(u16x8*)&xbuf[n * XS + c0] = p;
  }
}

// ---------------------------------------------------------------------------
// A1: ego -> out_o (broadcast) + Q (ws). grid = cnt*2, 256 thr.
// ---------------------------------------------------------------------------
__global__ __launch_bounds__(256, 2) void ca_ego(
    const float* __restrict__ ego, const float* __restrict__ b_oo,
    const u16* __restrict__ WCQ, u16* __restrict__ Qws,
    float* __restrict__ out, int bk0) {
  const int gid = blockIdx.x;
  const int bkl = gid >> 1, nh = gid & 1;
  const int bk = bk0 + bkl, b = bk >> 5, kk = bk & 31;
  const int t = threadIdx.x;
  const int lane = t & 63, wave = t >> 6;
  const int col = lane & 15, quad = lane >> 4;

  __shared__ u16 smem[32 * XS * 2];   // xbuf | qbuf
  u16* xbuf = smem;
  u16* qbuf = smem + 32 * XS;

  stage_x(ego + ((size_t)(b * 32 + kk) * 256) * 64 + nh * 32, xbuf, t);
  __syncthreads();

  f32x4 acc[8][2];
  gemm_run<8>(WCQ, xbuf, wave, col, quad, acc);

  float* outO = out + 4194304;
#pragma unroll
  for (int mt = 0; mt < 4; ++mt) {    // fused rows: out_o broadcast
    const int f = wave * 64 + mt * 16 + quad * 4;
#pragma unroll
    for (int nt = 0; nt < 2; ++nt) {
      const int n = nh * 32 + nt * 16 + col;
#pragma unroll
      for (int r = 0; r < 4; ++r) {
        const float v = acc[mt][nt][r] + b_oo[f + r];
        const size_t base = (size_t)((b * 8) * 32 + kk) * 16384 + (f + r) * 64 + n;
#pragma unroll
        for (int l = 0; l < 8; ++l) outO[base + (size_t)l * 524288] = v;
      }
    }
  }
#pragma unroll
  for (int mt = 4; mt < 8; ++mt) {    // q rows -> qbuf [n][o]
    const int ob = wave * 64 + (mt - 4) * 16 + quad * 4;
#pragma unroll
    for (int nt = 0; nt < 2; ++nt) {
      const int n = nt * 16 + col;
      u16x4 p;
#pragma unroll
      for (int r = 0; r < 4; ++r) p[r] = f2bf(acc[mt][nt][r]);
      *(u16x4*)&qbuf[n * XS + ob] = p;
    }
  }
  __syncthreads();
  // qbuf -> ws, coalesced
  u16* Qp = Qws + (size_t)(bkl * 64 + nh * 32) * 256;
#pragma unroll
  for (int j = 0; j < 4; ++j) {
    const int idx = t + j * 256;
    const int p = idx >> 5, cc = (idx & 31) * 8;
    *(u16x8*)&Qp[p * 256 + cc] = *(const u16x8*)&qbuf[p * XS + cc];
  }
}

// ---------------------------------------------------------------------------
// A2: other -> KV (ws, [pix][512] bf16: k 0..255, v 256..511).
// grid = cnt*16 (bkl, l, nh), 256 thr.
// ---------------------------------------------------------------------------
__global__ __launch_bounds__(256, 3) void ca_kv(
    const float* __restrict__ other, const u16* __restrict__ WKV,
    u16* __restrict__ KVws, int bk0) {
  const int gid = blockIdx.x;
  const int nh = gid & 1, l = (gid >> 1) & 7, bkl = gid >> 4;
  const int bk = bk0 + bkl, b = bk >> 5, kk = bk & 31;
  const int t = threadIdx.x;
  const int lane = t & 63, wave = t >> 6;
  const int col = lane & 15, quad = lane >> 4;

  __shared__ u16 smem[32 * XS + 32 * KVS];
  u16* xbuf = smem;
  u16* kbuf = smem + 32 * XS;

  stage_x(other + ((size_t)((b * 8 + l) * 32 + kk) * 256) * 64 + nh * 32, xbuf, t);
  __syncthreads();

  f32x4 acc[8][2];
  gemm_run<8>(WKV, xbuf, wave, col, quad, acc);
#pragma unroll
  for (int mt = 0; mt < 8; ++mt) {
    const int ob = (wave * 8 + mt) * 16 + quad * 4;
#pragma unroll
    for (int nt = 0; nt < 2; ++nt) {
      const int n = nt * 16 + col;
      u16x4 p;
#pragma unroll
      for (int r = 0; r < 4; ++r) p[r] = f2bf(acc[mt][nt][r]);
      *(u16x4*)&kbuf[n * KVS + ob] = p;
    }
  }
  __syncthreads();
  // kbuf -> ws, coalesced: 8 chunks of 16B per thread
  u16* KVp = KVws + ((size_t)(bkl * 8 + l) * 64 + nh * 32) * 512;
#pragma unroll
  for (int j = 0; j < 8; ++j) {
    const int idx = t + j * 256;
    const int p = idx >> 6, cc = (idx & 63) * 8;
    *(u16x8*)&KVp[p * 512 + cc] = *(const u16x8*)&kbuf[p * KVS + cc];
  }
}

// ---------------------------------------------------------------------------
// B: attention (registers only, prefetched) + out_e GEMM.
// grid = cnt*2 (bkl, nh), 256 thr; thread = (pixel an, head ah).
// ---------------------------------------------------------------------------
__global__ __launch_bounds__(256, 2) void ca_attn(
    const u16* __restrict__ Qws, const u16* __restrict__ KVws,
    const float* __restrict__ b_oe, const u16* __restrict__ WOE,
    float* __restrict__ out, int bk0) {
  const int gid = blockIdx.x;
  const int bkl = gid >> 1, nh = gid & 1;
  const int bk = bk0 + bkl, b = bk >> 5, kk = bk & 31;
  const int t = threadIdx.x;
  const int lane = t & 63, wave = t >> 6;
  const int col = lane & 15, quad = lane >> 4;
  const int an = t & 31, ah = t >> 5;

  __shared__ u16 xbuf[32 * XS];

  // q -> registers
  const u16* Qp = Qws + (size_t)(bkl * 64 + nh * 32 + an) * 256 + ah * 32;
  float qf[32];
#pragma unroll
  for (int jj = 0; jj < 4; ++jj) {
    u16x8 u = *(const u16x8*)&Qp[jj * 8];
#pragma unroll
    for (int e = 0; e < 8; ++e) qf[jj * 8 + e] = bf2f(u[e]);
  }

  const u16* kvb = KVws + ((size_t)(bkl * 8) * 64 + nh * 32 + an) * 512 + ah * 32;
  u16x8 ck[4], cv[4];
#pragma unroll
  for (int jj = 0; jj < 4; ++jj) {
    ck[jj] = *(const u16x8*)&kvb[jj * 8];
    cv[jj] = *(const u16x8*)&kvb[256 + jj * 8];
  }

  float m_run = -3.0e38f, s_run = 0.f;
  float oacc[32];
#pragma unroll
  for (int c = 0; c < 32; ++c) oacc[c] = 0.f;

#pragma unroll
  for (int l = 0; l < 8; ++l) {
    // prefetch agent l+1 (clamped; redundant last iter, always in-bounds)
    const int ln = (l < 7) ? (l + 1) : 7;
    const u16* pn = kvb + (size_t)ln * 32768;
    u16x8 nk_[4], nv_[4];
#pragma unroll
    for (int jj = 0; jj < 4; ++jj) {
      nk_[jj] = *(const u16x8*)&pn[jj * 8];
      nv_[jj] = *(const u16x8*)&pn[256 + jj * 8];
    }
    float sc = 0.f;
#pragma unroll
    for (int jj = 0; jj < 4; ++jj)
#pragma unroll
      for (int e = 0; e < 8; ++e) sc += qf[jj * 8 + e] * bf2f(ck[jj][e]);
    sc *= 0.17677669529663687f;
    const float mnew = fmaxf(m_run, sc);
    const float p = __expf(sc - mnew);
    const float al = __expf(m_run - mnew);
    s_run = s_run * al + p;
#pragma unroll
    for (int jj = 0; jj < 4; ++jj)
#pragma unroll
      for (int e = 0; e < 8; ++e)
        oacc[jj * 8 + e] = oacc[jj * 8 + e] * al + p * bf2f(cv[jj][e]);
    m_run = mnew;
#pragma unroll
    for (int jj = 0; jj < 4; ++jj) { ck[jj] = nk_[jj]; cv[jj] = nv_[jj]; }
  }

  {
    const float inv = 1.f / s_run;
#pragma unroll
    for (int jj = 0; jj < 4; ++jj) {
      u16x8 p;
#pragma unroll
      for (int e = 0; e < 8; ++e) p[e] = f2bf(oacc[jj * 8 + e] * inv);
      *(u16x8*)&xbuf[an * XS + ah * 32 + jj * 8] = p;
    }
  }
  __syncthreads();

  f32x4 acc[4][2];
  gemm_run<4>(WOE, xbuf, wave, col, quad, acc);
#pragma unroll
  for (int mt = 0; mt < 4; ++mt) {
    const int ob = (wave * 4 + mt) * 16 + quad * 4;
#pragma unroll
    for (int nt = 0; nt < 2; ++nt) {
      const int n = nh * 32 + nt * 16 + col;
#pragma unroll
      for (int r = 0; r < 4; ++r)
        out[(size_t)((b * 32 + kk) * 256 + ob + r) * 64 + n] =
            acc[mt][nt][r] + b_oe[ob + r];
    }
  }
}

// ---------------------------------------------------------------------------
extern "C" void kernel_launch(void* const* d_in, const int* in_sizes, int n_in,
                              void* d_out, int out_size, void* d_ws,
                              size_t ws_size, hipStream_t stream) {
  const float* ego    = (const float*)d_in[0];
  const float* other  = (const float*)d_in[1];
  const float* Wqkv_e = (const float*)d_in[2];
  const float* Wqkv_o = (const float*)d_in[3];
  const float* Woe    = (const float*)d_in[4];
  const float* boe    = (const float*)d_in[5];
  const float* Woo    = (const float*)d_in[6];
  const float* boo    = (const float*)d_in[7];
  float* out = (float*)d_out;

  u16* WCQ  = (u16*)d_ws;            // [512][256]
  u16* WKV  = WCQ + 512 * 256;       // [512][256]
  u16* WOET = WKV + 512 * 256;       // [256][256]
  u16* Qws  = WOET + 256 * 256;      // nk*64*256
  // choose chunk width nk over the 256-wide (b,k) axis to fit ws
  const size_t fixed = (size_t)(512 * 256 + 512 * 256 + 256 * 256) * 2;
  const size_t per_bk = (size_t)64 * 256 * 2 + (size_t)8 * 64 * 512 * 2; // Q + KV
  long nk_l = (ws_size > fixed) ? (long)((ws_size - fixed) / per_bk) : 1;
  if (nk_l < 1) nk_l = 1;
  if (nk_l > 256) nk_l = 256;
  const int nk = (int)nk_l;
  u16* KVws = Qws + (size_t)nk * 64 * 256;

  ca_setup_fuse<<<256, 256, 0, stream>>>(Wqkv_e, Woo, WCQ);
  ca_setup_trans<<<1024, 256, 0, stream>>>(Wqkv_e, Wqkv_o, Woe, WCQ, WKV, WOET);

  for (int bk0 = 0; bk0 < 256; bk0 += nk) {
    const int cnt = (bk0 + nk <= 256) ? nk : (256 - bk0);
    ca_ego <<<cnt * 2, 256, 0, stream>>>(ego, boo, WCQ, Qws, out, bk0);
    ca_kv  <<<cnt * 16, 256, 0, stream>>>(other, WKV, KVws, bk0);
    ca_attn<<<cnt * 2, 256, 0, stream>>>(Qws, KVws, boe, WOET, out, bk0);
  }
}